// Round 2
// baseline (102.994 us; speedup 1.0000x reference)
//
#include <hip/hip_runtime.h>

// NEAT windowed-DAG forward, 4-lanes-per-element, u-domain recurrence.
//   values[0:16] = x; for i in 0..511: v = tanh(dot(values[i:i+16], w[i]) + b[i]) * r[i]
//   out = values[T-64:T]
//
// R8: R7 proved the kernel is latency-bound on the per-node serial chain
// (wall 214 cyc/node >> 30 cyc issue; more waves didn't help). This version
// minimizes the chain to fma -> exp2 -> add -> rcp (4 hops):
//  * u-domain: carry u = sigmoid(-2z); t = 1-2u folded into staged weights
//    W" = -2*kScale*w*r_src and bias B" = kScale*(b + sum_j w*r_src)
//    (no tanh-decode fma on the chain). Inputs enter as u_x=(1-x)/2; outputs
//    decode o = r*(1-2u) at store time.
//  * late dependent term: lane3's .w dot-term (the only dependency on the
//    previous node) is masked out of the 4-fma partial + DPP reduce (all
//    off-chain, overlaps the previous node's chain) and injected after the
//    reduce: acc = fma(u_prev, dpp_bcast3(W.w), sf).
//  * window insert (cndmask) is consumed 2 nodes later -> off-chain.
// LDS delivery identical to R7: 5 ds_read_b128/quad, depth-3 rotating sets,
// exact counted s_waitcnt lgkmcnt(15).

typedef float v4f __attribute__((ext_vector_type(4)));

constexpr int kNOut     = 64;
constexpr int kBatch    = 32768;
constexpr int kQStrideF = 80;                       // floats per quad block (320 B)
constexpr int kLdsFloats = (128 + 3) * kQStrideF;   // 128 quads + 3 pad (prefetch overrun)
constexpr float kScale  = 2.8853900817779268f;      // 2*log2(e)

// quad_perm DPP through the builtin so the compiler handles hazard nops.
#define QPERM(X, CTRL) __int_as_float(__builtin_amdgcn_update_dpp(            \
    __float_as_int(X), __float_as_int(X), (CTRL), 0xF, 0xF, false))

// Issue the 5 ds_read_b128 for quad S: per-lane weights of nodes c=0..3 at
// byte offsets c*64 (+ lane j*16 folded into `a`), plus the 4-way-replicated
// bias block at +256 (lane j reads replica j: same data, distinct banks).
#define PREFQ(S) {                                                            \
    asm volatile(                                                             \
      "ds_read_b128 %0, %5 offset:0\n\t"                                      \
      "ds_read_b128 %1, %5 offset:64\n\t"                                     \
      "ds_read_b128 %2, %5 offset:128\n\t"                                    \
      "ds_read_b128 %3, %5 offset:192\n\t"                                    \
      "ds_read_b128 %4, %5 offset:256"                                        \
      : "=&v"(qw0[S]), "=&v"(qw1[S]), "=&v"(qw2[S]), "=&v"(qw3[S]),           \
        "=&v"(qb[S])                                                          \
      : "v"(a));                                                              \
    a += kQStrideF * 4; }

// After PREFQ of quad Q+3, the 15 newer reads (quads Q+1..Q+3) may remain
// outstanding; in-order DS returns make lgkmcnt(15) == "set Q landed".
#define WAITQ(S)                                                              \
    asm volatile("s_waitcnt lgkmcnt(15)"                                      \
      : "+v"(qw0[S]), "+v"(qw1[S]), "+v"(qw2[S]), "+v"(qw3[S]), "+v"(qb[S]));

// One node, u-domain. WA..WD = lane's window quarter (u-encoded values).
// INIV = B"/4 (identical in all lanes; 4-lane sum restores B").
// Off-chain: masked 4-fma partial, 2-stage DPP reduce, W15 broadcast, shift.
// Chain (u_prev -> u): fma -> exp2 -> add -> rcp.  Insert has 2-node slack.
#define NODE1(QW, INIV, WA, WB, WC, WD) {                                     \
    float wmask = is_l3 ? 0.0f : (QW).w;    /* drop dependent term */         \
    float w15b  = QPERM((QW).w, 0xFF);      /* bcast lane3 .w weight */       \
    float p = fmaf((WA), (QW).x, (INIV));                                     \
    p = fmaf((WB), (QW).y, p);                                                \
    p = fmaf((WC), (QW).z, p);                                                \
    p = fmaf((WD), wmask, p);                                                 \
    float s1 = p + QPERM(p, 0xB1);          /* quad_perm:[1,0,3,2] */         \
    float sf = s1 + QPERM(s1, 0x4E);        /* quad_perm:[2,3,0,1] */         \
    float mg = QPERM((WA), 0x39);           /* quad_perm:[1,2,3,0] */         \
    float acc = fmaf(u_prev, w15b, sf);     /* chain starts here */           \
    float ex  = __builtin_amdgcn_exp2f(acc);                                  \
    float un  = __builtin_amdgcn_rcpf(ex + 1.0f);                             \
    u_prev = un;                                                              \
    (WA) = is_l3 ? un : mg; }

// Quad of nodes: prefetch quad S+3, wait for quad S, run 4 nodes with the
// window names rotating (period 4).
#define NODEQ(S) {                                                            \
    PREFQ(((S) + 3) & 3)                                                      \
    WAITQ(S)                                                                  \
    v4f f0 = qw0[S], f1 = qw1[S], f2 = qw2[S], f3 = qw3[S], fb = qb[S];       \
    NODE1(f0, fb.x, r0, r1, r2, r3)                                           \
    NODE1(f1, fb.y, r1, r2, r3, r0)                                           \
    NODE1(f2, fb.z, r2, r3, r0, r1)                                           \
    NODE1(f3, fb.w, r3, r0, r1, r2) }

__global__ __launch_bounds__(512) void neat_fwd(
    const float* __restrict__ x,      // [B, 16]
    const float* __restrict__ w,      // [512, 16]
    const float* __restrict__ bias,   // [512]
    const float* __restrict__ resp,   // [512]
    float* __restrict__ out)          // [B, 64]
{
    __shared__ alignas(16) float ldsw[kLdsFloats];
    __shared__ float rst[512];
    __shared__ float sums[512];       // per-node sum_j w_ij * rho_j (unscaled)

    const int t  = threadIdx.x;       // 0..511 (8 waves)
    const int jl = t & 3;             // lane within quad
    const bool is_l3 = (jl == 3);

    // ---- Stage: raw resp first ----
    rst[t] = resp[t];
    __syncthreads();

    // ---- Stage weights W" = -2*kScale*w*rho, and per-node sums via DPP ----
    const float4* __restrict__ w4 = reinterpret_cast<const float4*>(w);
    #pragma unroll
    for (int k = 0; k < 4; ++k) {
        int i4 = t + k * 512;                 // [0, 2048) float4s of w
        float4 v = w4[i4];
        int n = i4 >> 2, k4 = i4 & 3;
        int s0 = n + 4 * k4;                  // global src idx of component .x
        float rho0 = (s0 + 0 < 16) ? 1.0f : rst[s0 - 16];
        float rho1 = (s0 + 1 < 16) ? 1.0f : rst[s0 - 15];
        float rho2 = (s0 + 2 < 16) ? 1.0f : rst[s0 - 14];
        float rho3 = (s0 + 3 < 16) ? 1.0f : rst[s0 - 13];
        float wr0 = v.x * rho0, wr1 = v.y * rho1,
              wr2 = v.z * rho2, wr3 = v.w * rho3;
        // quarter partial of sum_j w*rho; threads 4m..4m+3 hold the 4
        // quarters of node n (k4 == t&3) -> quad DPP reduce.
        float ps = (wr0 + wr1) + (wr2 + wr3);
        ps += QPERM(ps, 0xB1);
        ps += QPERM(ps, 0x4E);
        if (jl == 0) sums[n] = ps;
        const float m2k = -2.0f * kScale;
        float4 sc = make_float4(wr0 * m2k, wr1 * m2k, wr2 * m2k, wr3 * m2k);
        *reinterpret_cast<float4*>(
            &ldsw[(n >> 2) * kQStrideF + (n & 3) * 16 + k4 * 4]) = sc;
    }
    __syncthreads();

    {   // bias block: 4 replicas of B"/4 = kScale*(b + sum w*rho)/4 per node
        float Bq = (bias[t] + sums[t]) * (kScale * 0.25f);
        int q = t >> 2, s = t & 3;
        #pragma unroll
        for (int rep = 0; rep < 4; ++rep)
            ldsw[q * kQStrideF + 64 + rep * 4 + s] = Bq;
    }

    // ---- Per-thread state: window quarter (u-encoded) + output r-vectors ----
    const int e = blockIdx.x * 128 + (t >> 2);     // batch element
    const float4 xi = reinterpret_cast<const float4*>(x)[e * 4 + jl];
    // u-encode inputs: u = (1 - x)/2  (exact affine; t = 1-2u recovers x)
    float r0 = fmaf(-0.5f, xi.x, 0.5f);
    float r1 = fmaf(-0.5f, xi.y, 0.5f);
    float r2 = fmaf(-0.5f, xi.z, 0.5f);
    float r3 = fmaf(-0.5f, xi.w, 0.5f);

    // resp for output nodes 448..511: rvK[c] = resp[448 + 16K + 4*jl + c]
    const float4* __restrict__ rr4 = reinterpret_cast<const float4*>(resp);
    const float4 rv0 = rr4[112 + jl], rv1 = rr4[116 + jl],
                 rv2 = rr4[120 + jl], rv3 = rr4[124 + jl];

    float* __restrict__ op = out + (size_t)e * kNOut + jl * 4;

    // chain register: u of window position 15 (= lane3's r3, broadcast)
    float u_prev = QPERM(r3, 0xFF);

    __syncthreads();   // drains staging ds ops (compiler lgkmcnt(0))

    // DS byte address cursor (+ lane's j*16 weight offset folded in).
    unsigned int a = (unsigned int)(unsigned long long)(&ldsw[0])
                   + (unsigned int)(jl << 4);

    v4f qw0[4], qw1[4], qw2[4], qw3[4], qb[4];
    PREFQ(0) PREFQ(1) PREFQ(2)     // quads 0,1,2 in flight

    #pragma unroll 1
    for (int g = 0; g < 32; ++g) {
        NODEQ(0) NODEQ(1) NODEQ(2) NODEQ(3)
        // After the group, lane jl's r0..r3 = u-values of nodes 16g+4jl+{0..3}.
        if (g >= 28) {
            float4 rv = (g == 28) ? rv0 : (g == 29) ? rv1
                      : (g == 30) ? rv2 : rv3;
            float t0 = fmaf(-2.0f, r0, 1.0f);
            float t1 = fmaf(-2.0f, r1, 1.0f);
            float t2 = fmaf(-2.0f, r2, 1.0f);
            float t3 = fmaf(-2.0f, r3, 1.0f);
            *reinterpret_cast<float4*>(op + (g - 28) * 16) =
                make_float4(t0 * rv.x, t1 * rv.y, t2 * rv.z, t3 * rv.w);
        }
    }

    // Drain overrun prefetches (pad quads 128..130).
    asm volatile("s_waitcnt lgkmcnt(0)" ::: "memory");
}

extern "C" void kernel_launch(void* const* d_in, const int* in_sizes, int n_in,
                              void* d_out, int out_size, void* d_ws, size_t ws_size,
                              hipStream_t stream) {
    const float* x    = (const float*)d_in[0];
    const float* w    = (const float*)d_in[1];
    const float* bias = (const float*)d_in[2];
    const float* resp = (const float*)d_in[3];
    float* out = (float*)d_out;
    // in_sizes[4] (src_idx) encodes the fixed windowed topology; hardcoded above.
    dim3 block(512);
    dim3 grid((kBatch * 4) / 512);   // 256 blocks -> 1 per CU, 8 waves/CU
    hipLaunchKernelGGL(neat_fwd, grid, block, 0, stream, x, w, bias, resp, out);
}

// Round 3
// 89.346 us; speedup vs baseline: 1.1528x; 1.1528x over previous
//
#include <hip/hip_runtime.h>

// NEAT windowed-DAG forward, 2-lanes-per-element (pair-split), u-domain.
//   values[0:16] = x; for i in 0..511: v = tanh(dot(values[i:i+16], w[i]) + b[i]) * r[i]
//   out = values[T-64:T]
//
// R9: R7/R8 established the kernel is per-SIMD ISSUE-bound (wall tracks
// instruction count; VALUBusy ~66% at 2 waves/SIMD; chain-shortening was
// neutral). Quad-split pays 13 overhead instrs per 4 useful fmas. Pair-split
// halves redundancy: lane j holds window positions 8j..8j+8; per node =
// 8 useful fmas + ONE dpp-add reduce + chain + 1-reg migration = 15 instr
// per 32 elements (0.47/el/node vs quad's 1.06). 1024 waves = 1 wave/SIMD
// on ALL SIMDs (256 blocks x 256 thr). Dependent term sits in lane1's 8th
// fma (R8 proved inject tricks are wasted issue). Bias = B"/2 in both
// lanes' fma init (no cndmask).
//
// u-domain (from R8, verified): carry u = sigmoid(-2z); staged weights
// W" = -2*kScale*w*rho_src, meta Bh = kScale*(b + sum_j w*rho)/2; inputs
// u=(1-x)/2; outputs o = r*(1-2u).
//
// LDS delivery: per 2-node group = 4 per-lane weight b128 (natural
// row-major: lane j reads floats 8j..8j+8 of each node) + 1 meta b64
// (replica placed at +32B so one cursor serves both lanes). 5 reads/group,
// 4 rotating sets, depth-3 prefetch, exact counted s_waitcnt lgkmcnt(15) —
// byte-identical invariant to the proven R6-R8 pipeline.

typedef float v4f __attribute__((ext_vector_type(4)));
typedef float v2f __attribute__((ext_vector_type(2)));

constexpr int kNOut     = 64;
constexpr int kBatch    = 32768;
constexpr int kGStrideF = 48;                       // floats per 2-node group (192 B)
constexpr int kLdsFloats = (256 + 3) * kGStrideF;   // 256 groups + prefetch overrun pad
constexpr float kScale  = 2.8853900817779268f;      // 2*log2(e)

// quad_perm DPP through the builtin so the compiler handles hazard nops.
#define QPERM(X, CTRL) __int_as_float(__builtin_amdgcn_update_dpp(            \
    __float_as_int(X), __float_as_int(X), (CTRL), 0xF, 0xF, false))

// Issue the 5 ds_read for group S (nodes 2q,2q+1): per-lane weight halves
// of both nodes + meta b64 (BhA,BhB). Cursor a = group_base + 32*jl, so
// lane0 meta lands at byte 128 and lane1 at its replica at byte 160.
#define PREF(S) {                                                             \
    asm volatile(                                                             \
      "ds_read_b128 %0, %5 offset:0\n\t"                                      \
      "ds_read_b128 %1, %5 offset:16\n\t"                                     \
      "ds_read_b128 %2, %5 offset:64\n\t"                                     \
      "ds_read_b128 %3, %5 offset:80\n\t"                                     \
      "ds_read_b64  %4, %5 offset:128"                                        \
      : "=&v"(qa[S]), "=&v"(qb[S]), "=&v"(qc[S]), "=&v"(qd[S]), "=&v"(qm[S])  \
      : "v"(a));                                                              \
    a += kGStrideF * 4; }

// After PREF of group G+3, the 15 newer reads (groups G+1..G+3) may remain
// outstanding; in-order DS returns make lgkmcnt(15) == "set G landed".
#define WAITG(S)                                                              \
    asm volatile("s_waitcnt lgkmcnt(15)"                                      \
      : "+v"(qa[S]), "+v"(qb[S]), "+v"(qc[S]), "+v"(qd[S]), "+v"(qm[S]));

// One node. W0..W7 = lane's window half in age order (W0 oldest; lane1's W7
// = previous node's u -> consumed by the LAST fma, the only serial-chain op).
// BH = B"/2 enters both lanes' fma init (2-lane reduce restores B").
// Reduce: sf = p + swap(p) (one dpp-add pair). Migration: lane0's vacated
// W0 pulls lane1's W0 (the boundary value); lane1's W0 gets the new u.
#define NODE1(WLO, WHI, BH, W0,W1,W2,W3,W4,W5,W6,W7) {                        \
    float p = fmaf((W0), (WLO).x, (BH));                                      \
    p = fmaf((W1), (WLO).y, p);                                               \
    p = fmaf((W2), (WLO).z, p);                                               \
    p = fmaf((W3), (WLO).w, p);                                               \
    p = fmaf((W4), (WHI).x, p);                                               \
    p = fmaf((W5), (WHI).y, p);                                               \
    p = fmaf((W6), (WHI).z, p);                                               \
    p = fmaf((W7), (WHI).w, p);                                               \
    float sf = p + QPERM(p, 0xB1);          /* quad_perm:[1,0,3,2] */         \
    float ex = __builtin_amdgcn_exp2f(sf);                                    \
    float un = __builtin_amdgcn_rcpf(ex + 1.0f);                              \
    float mg = QPERM((W0), 0xB1);           /* pull partner's W0 */           \
    (W0) = is_l1 ? un : mg; }

// 2-node group: prefetch group G+3, wait for group G, run both nodes.
// O* / P* = window names rotated for nodes 2G, 2G+1 (period 8).
#define GROUP(G, O0,O1,O2,O3,O4,O5,O6,O7, P0,P1,P2,P3,P4,P5,P6,P7) {          \
    PREF(((G) + 3) & 3)                                                       \
    WAITG((G) & 3)                                                            \
    NODE1(qa[(G) & 3], qb[(G) & 3], qm[(G) & 3].x,                            \
          O0,O1,O2,O3,O4,O5,O6,O7)                                            \
    NODE1(qc[(G) & 3], qd[(G) & 3], qm[(G) & 3].y,                            \
          P0,P1,P2,P3,P4,P5,P6,P7) }

__global__ __launch_bounds__(256) void neat_fwd(
    const float* __restrict__ x,      // [B, 16]
    const float* __restrict__ w,      // [512, 16]
    const float* __restrict__ bias,   // [512]
    const float* __restrict__ resp,   // [512]
    float* __restrict__ out)          // [B, 64]
{
    __shared__ alignas(16) float ldsw[kLdsFloats];
    __shared__ float rst[512];
    __shared__ float sums[512];       // per-node sum_j w_ij * rho_j (unscaled)

    const int t  = threadIdx.x;       // 0..255 (4 waves)
    const int jl = t & 1;             // lane within pair
    const bool is_l1 = (jl == 1);

    // ---- Stage: raw resp first ----
    rst[t] = resp[t];
    rst[t + 256] = resp[t + 256];
    __syncthreads();

    // ---- Stage weights W" = -2*kScale*w*rho + per-node sums via DPP ----
    const float4* __restrict__ w4 = reinterpret_cast<const float4*>(w);
    #pragma unroll
    for (int k = 0; k < 8; ++k) {
        int i4 = t + k * 256;                 // [0, 2048) float4s of w
        float4 v = w4[i4];
        int n = i4 >> 2, k4 = i4 & 3;
        int s0 = n + 4 * k4;                  // global value idx of component .x
        float rho0 = (s0 + 0 < 16) ? 1.0f : rst[s0 - 16];
        float rho1 = (s0 + 1 < 16) ? 1.0f : rst[s0 - 15];
        float rho2 = (s0 + 2 < 16) ? 1.0f : rst[s0 - 14];
        float rho3 = (s0 + 3 < 16) ? 1.0f : rst[s0 - 13];
        float wr0 = v.x * rho0, wr1 = v.y * rho1,
              wr2 = v.z * rho2, wr3 = v.w * rho3;
        // quarter partial of sum_j w*rho; threads 4m..4m+3 hold the 4
        // quarters of node n -> quad DPP reduce.
        float ps = (wr0 + wr1) + (wr2 + wr3);
        ps += QPERM(ps, 0xB1);
        ps += QPERM(ps, 0x4E);
        if ((t & 3) == 0) sums[n] = ps;
        const float m2k = -2.0f * kScale;
        float4 sc = make_float4(wr0 * m2k, wr1 * m2k, wr2 * m2k, wr3 * m2k);
        *reinterpret_cast<float4*>(
            &ldsw[(n >> 1) * kGStrideF + (n & 1) * 16 + k4 * 4]) = sc;
    }
    __syncthreads();

    // meta: Bh = kScale*(b + sum w*rho)/2 per node, two replicas per group
    #pragma unroll
    for (int k = 0; k < 2; ++k) {
        int n = t + k * 256;
        float Bh = (bias[n] + sums[n]) * (kScale * 0.5f);
        int q = n >> 1, s = n & 1;
        ldsw[q * kGStrideF + 32 + s] = Bh;   // lane0's replica (byte 128)
        ldsw[q * kGStrideF + 40 + s] = Bh;   // lane1's replica (byte 160)
    }

    // ---- Per-thread state: window half (u-encoded) ----
    const int e = blockIdx.x * 128 + (t >> 1);     // batch element
    const float4 xa = reinterpret_cast<const float4*>(x)[e * 4 + 2 * jl];
    const float4 xb = reinterpret_cast<const float4*>(x)[e * 4 + 2 * jl + 1];
    // u-encode inputs: u = (1 - x)/2  (exact affine; t = 1-2u recovers x)
    float r0 = fmaf(-0.5f, xa.x, 0.5f);
    float r1 = fmaf(-0.5f, xa.y, 0.5f);
    float r2 = fmaf(-0.5f, xa.z, 0.5f);
    float r3 = fmaf(-0.5f, xa.w, 0.5f);
    float r4 = fmaf(-0.5f, xb.x, 0.5f);
    float r5 = fmaf(-0.5f, xb.y, 0.5f);
    float r6 = fmaf(-0.5f, xb.z, 0.5f);
    float r7 = fmaf(-0.5f, xb.w, 0.5f);

    const float4* __restrict__ rr4 = reinterpret_cast<const float4*>(resp);
    float* __restrict__ op = out + (size_t)e * kNOut + jl * 8;

    __syncthreads();   // drains staging ds ops (compiler lgkmcnt(0))

    // DS byte cursor (+ lane's 32B weight-half offset folded in).
    unsigned int a = (unsigned int)(unsigned long long)(&ldsw[0])
                   + (unsigned int)(jl << 5);

    v4f qa[4], qb[4], qc[4], qd[4];
    v2f qm[4];
    PREF(0) PREF(1) PREF(2)     // groups 0,1,2 in flight

    #pragma unroll 1
    for (int g = 0; g < 32; ++g) {
        // 16 nodes = 8 groups; rotation start for node n is n&7.
        GROUP(0, r0,r1,r2,r3,r4,r5,r6,r7,  r1,r2,r3,r4,r5,r6,r7,r0)
        GROUP(1, r2,r3,r4,r5,r6,r7,r0,r1,  r3,r4,r5,r6,r7,r0,r1,r2)
        GROUP(2, r4,r5,r6,r7,r0,r1,r2,r3,  r5,r6,r7,r0,r1,r2,r3,r4)
        GROUP(3, r6,r7,r0,r1,r2,r3,r4,r5,  r7,r0,r1,r2,r3,r4,r5,r6)
        GROUP(4, r0,r1,r2,r3,r4,r5,r6,r7,  r1,r2,r3,r4,r5,r6,r7,r0)
        GROUP(5, r2,r3,r4,r5,r6,r7,r0,r1,  r3,r4,r5,r6,r7,r0,r1,r2)
        GROUP(6, r4,r5,r6,r7,r0,r1,r2,r3,  r5,r6,r7,r0,r1,r2,r3,r4)
        GROUP(7, r6,r7,r0,r1,r2,r3,r4,r5,  r7,r0,r1,r2,r3,r4,r5,r6)
        // After the group of 16, lane jl's r0..r7 = u of nodes 16g+8jl+{0..7}
        // in age order (names realigned: period 8, 16 nodes = 2 rotations).
        if (g >= 28) {
            int m = g - 28;
            const float4 ra = rr4[112 + 4 * m + 2 * jl];
            const float4 rb = rr4[112 + 4 * m + 2 * jl + 1];
            float4 o0 = make_float4(fmaf(-2.0f, r0, 1.0f) * ra.x,
                                    fmaf(-2.0f, r1, 1.0f) * ra.y,
                                    fmaf(-2.0f, r2, 1.0f) * ra.z,
                                    fmaf(-2.0f, r3, 1.0f) * ra.w);
            float4 o1 = make_float4(fmaf(-2.0f, r4, 1.0f) * rb.x,
                                    fmaf(-2.0f, r5, 1.0f) * rb.y,
                                    fmaf(-2.0f, r6, 1.0f) * rb.z,
                                    fmaf(-2.0f, r7, 1.0f) * rb.w);
            *reinterpret_cast<float4*>(op + 16 * m)     = o0;
            *reinterpret_cast<float4*>(op + 16 * m + 4) = o1;
        }
    }

    // Drain overrun prefetches (pad groups 256..258).
    asm volatile("s_waitcnt lgkmcnt(0)" ::: "memory");
}

extern "C" void kernel_launch(void* const* d_in, const int* in_sizes, int n_in,
                              void* d_out, int out_size, void* d_ws, size_t ws_size,
                              hipStream_t stream) {
    const float* x    = (const float*)d_in[0];
    const float* w    = (const float*)d_in[1];
    const float* bias = (const float*)d_in[2];
    const float* resp = (const float*)d_in[3];
    float* out = (float*)d_out;
    // in_sizes[4] (src_idx) encodes the fixed windowed topology; hardcoded above.
    dim3 block(256);
    dim3 grid(kBatch / 128);   // 256 blocks -> 1/CU, 4 waves/CU = 1 per SIMD
    hipLaunchKernelGGL(neat_fwd, grid, block, 0, stream, x, w, bias, resp, out);
}